// Round 4
// baseline (467.290 us; speedup 1.0000x reference)
//
#include <hip/hip_runtime.h>

// 12-bit ripple-carry adder over {0,1}-valued float32.
// Semantics == integer add: pack 12 bits (index 11 = LSB), add, unpack 13 bits.
// Inputs are exactly 0.0f / 1.0f. 1.0f = 0x3F800000: bit 29 is set (bit 30 is
// NOT -- exponent 0x7F occupies bits 30..23 as 0111_1111). 0.0f -> all clear.
// Memory-bound: 620.8 MB total traffic -> ~100us floor at 6.3 TB/s achievable.

#define BATCH 4194304
#define BITS  12

__global__ __launch_bounds__(256) void adder12_kernel(
    const uint4* __restrict__ A,    // [BATCH][12] f32 viewed as 3x uint4/row
    const uint4* __restrict__ B,
    uint4* __restrict__ sums,       // [BATCH][12] f32 bit patterns
    unsigned* __restrict__ carry)   // [BATCH]
{
    const unsigned ONE = 0x3F800000u;  // 1.0f
    const long long stride = (long long)gridDim.x * blockDim.x;
    for (long long i = (long long)blockIdx.x * blockDim.x + threadIdx.x;
         i < BATCH; i += stride) {

        const uint4* a4 = A + i * 3;
        const uint4* b4 = B + i * 3;
        uint4 av0 = a4[0], av1 = a4[1], av2 = a4[2];
        uint4 bv0 = b4[0], bv1 = b4[1], bv2 = b4[2];

        unsigned au[12] = {av0.x, av0.y, av0.z, av0.w,
                           av1.x, av1.y, av1.z, av1.w,
                           av2.x, av2.y, av2.z, av2.w};
        unsigned bu[12] = {bv0.x, bv0.y, bv0.z, bv0.w,
                           bv1.x, bv1.y, bv1.z, bv1.w,
                           bv2.x, bv2.y, bv2.z, bv2.w};

        unsigned ua = 0u, ub = 0u;
        #pragma unroll
        for (int j = 0; j < 12; ++j) {
            // bit index 11 is the LSB (reference scans 11 -> 0);
            // bit 29 of the f32 pattern distinguishes 1.0f from 0.0f
            ua |= ((au[j] >> 29) & 1u) << (11 - j);
            ub |= ((bu[j] >> 29) & 1u) << (11 - j);
        }

        const unsigned s = ua + ub;   // 13-bit result

        unsigned of[12];
        #pragma unroll
        for (int j = 0; j < 12; ++j)
            of[j] = ((s >> (11 - j)) & 1u) ? ONE : 0u;

        uint4* o4 = sums + i * 3;
        o4[0] = make_uint4(of[0],  of[1],  of[2],  of[3]);
        o4[1] = make_uint4(of[4],  of[5],  of[6],  of[7]);
        o4[2] = make_uint4(of[8],  of[9],  of[10], of[11]);

        carry[i] = ((s >> 12) & 1u) ? ONE : 0u;
    }
}

extern "C" void kernel_launch(void* const* d_in, const int* in_sizes, int n_in,
                              void* d_out, int out_size, void* d_ws, size_t ws_size,
                              hipStream_t stream) {
    const uint4* A = (const uint4*)d_in[0];
    const uint4* B = (const uint4*)d_in[1];
    uint4* sums     = (uint4*)d_out;                          // BATCH*12 f32
    unsigned* carry = (unsigned*)d_out + (size_t)BATCH * 12;  // BATCH f32

    // Memory-bound: cap grid at 256 CU x 8 blocks/CU, grid-stride the rest.
    dim3 grid(2048), block(256);
    adder12_kernel<<<grid, block, 0, stream>>>(A, B, sums, carry);
}

// Round 6
// 462.267 us; speedup vs baseline: 1.0109x; 1.0109x over previous
//
#include <hip/hip_runtime.h>

// 12-bit ripple-carry adder over {0,1}-valued float32.
// Semantics == integer add: pack 12 bits (index 11 = LSB), add, unpack 13 bits.
// Inputs are exactly 0.0f / 1.0f; bit 29 of the f32 pattern distinguishes them.
//
// R4 post-mortem: thread-per-row direct access = 48 B lane stride -> 3x request
// amplification per vmem instruction -> 3.76 TB/s logical (165 us). Fix: LDS
// transpose staging so every global access is lane-stride-16B coalesced.
// LDS read/write at t*48 is conflict-free for b128 (lanes 0-7 cover all 32 banks).

#define BATCH   4194304
#define BITS    12
#define NBLOCKS 2048
#define NTILES  (BATCH / 256)          // 16384 tiles of 256 rows

__global__ __launch_bounds__(256) void adder12_kernel(
    const uint4* __restrict__ A4,      // [BATCH*3] uint4 view of [BATCH][12] f32
    const uint4* __restrict__ B4,
    uint4* __restrict__ S4,            // [BATCH*3] uint4 view of sums
    unsigned* __restrict__ carry)      // [BATCH]
{
    __shared__ uint4 sA[768];          // 256 rows x 48 B = 12 KB
    __shared__ uint4 sB[768];          // 12 KB

    const unsigned t = threadIdx.x;
    const unsigned ONE = 0x3F800000u;  // 1.0f

    for (unsigned tile = blockIdx.x; tile < NTILES; tile += NBLOCKS) {
        const size_t u4base  = (size_t)tile * 768;   // tile start, uint4 units
        const size_t rowbase = (size_t)tile * 256;

        // ---- stage in: fully coalesced (lane stride 16 B) ----
        #pragma unroll
        for (int k = 0; k < 3; ++k) {
            sA[t + 256u * k] = A4[u4base + t + 256u * k];
            sB[t + 256u * k] = B4[u4base + t + 256u * k];
        }
        __syncthreads();

        // ---- compute: each thread owns one row (LDS b128, conflict-free) ----
        uint4 a0 = sA[t * 3 + 0], a1 = sA[t * 3 + 1], a2 = sA[t * 3 + 2];
        uint4 b0 = sB[t * 3 + 0], b1 = sB[t * 3 + 1], b2 = sB[t * 3 + 2];

        unsigned au[12] = {a0.x, a0.y, a0.z, a0.w,
                           a1.x, a1.y, a1.z, a1.w,
                           a2.x, a2.y, a2.z, a2.w};
        unsigned bu[12] = {b0.x, b0.y, b0.z, b0.w,
                           b1.x, b1.y, b1.z, b1.w,
                           b2.x, b2.y, b2.z, b2.w};

        unsigned ua = 0u, ub = 0u;
        #pragma unroll
        for (int j = 0; j < 12; ++j) {
            // bit index 11 is the LSB (reference scans 11 -> 0);
            // bit 29 of the f32 pattern distinguishes 1.0f from 0.0f
            ua |= ((au[j] >> 29) & 1u) << (11 - j);
            ub |= ((bu[j] >> 29) & 1u) << (11 - j);
        }

        const unsigned s = ua + ub;    // 13-bit result

        unsigned of[12];
        #pragma unroll
        for (int j = 0; j < 12; ++j)
            of[j] = ((s >> (11 - j)) & 1u) ? ONE : 0u;

        const unsigned cv = ((s >> 12) & 1u) ? ONE : 0u;

        __syncthreads();               // all sA/sB reads done before overwrite

        sA[t * 3 + 0] = make_uint4(of[0], of[1], of[2],  of[3]);
        sA[t * 3 + 1] = make_uint4(of[4], of[5], of[6],  of[7]);
        sA[t * 3 + 2] = make_uint4(of[8], of[9], of[10], of[11]);
        __syncthreads();

        // ---- stage out: fully coalesced ----
        #pragma unroll
        for (int k = 0; k < 3; ++k)
            S4[u4base + t + 256u * k] = sA[t + 256u * k];
        carry[rowbase + t] = cv;

        __syncthreads();               // protect sA/sB before next tile's stage
    }
}

extern "C" void kernel_launch(void* const* d_in, const int* in_sizes, int n_in,
                              void* d_out, int out_size, void* d_ws, size_t ws_size,
                              hipStream_t stream) {
    const uint4* A = (const uint4*)d_in[0];
    const uint4* B = (const uint4*)d_in[1];
    uint4* sums     = (uint4*)d_out;                          // BATCH*12 f32
    unsigned* carry = (unsigned*)d_out + (size_t)BATCH * 12;  // BATCH f32

    dim3 grid(NBLOCKS), block(256);
    adder12_kernel<<<grid, block, 0, stream>>>(A, B, sums, carry);
}